// Round 1
// baseline (266.179 us; speedup 1.0000x reference)
//
#include <hip/hip_runtime.h>

#define NRELS 64
#define BLOCK 256

// Faithful sparsemax for d=3 (Martins & Astudillo 2016), matching the
// reference: sort desc, cumsum, ksup = sum of support booleans,
// tau = (cs[ksup-1]-1)/ksup, out = max(z - tau, 0).
__device__ __forceinline__ void sparsemax3(float z0, float z1, float z2,
                                           float& o0, float& o1, float& o2) {
    float lo01 = fminf(z0, z1), hi01 = fmaxf(z0, z1);
    float s2 = fminf(lo01, z2);          // min of all
    float mx = fmaxf(lo01, z2);
    float s0 = fmaxf(hi01, mx);          // max of all
    float s1 = fminf(hi01, mx);          // middle
    float cs2 = s0 + s1;
    float cs3 = cs2 + s2;
    // k=1 support condition (1 + s0 > s0) is always true.
    int k = 1 + (int)(1.0f + 2.0f * s1 > cs2) + (int)(1.0f + 3.0f * s2 > cs3);
    float csk = (k == 1) ? s0 : ((k == 2) ? cs2 : cs3);
    float tau = (csk - 1.0f) / (float)k;
    o0 = fmaxf(z0 - tau, 0.0f);
    o1 = fmaxf(z1 - tau, 0.0f);
    o2 = fmaxf(z2 - tau, 0.0f);
}

__device__ __forceinline__ void edge_compute(
    float p0, float p1, float p2,
    float q0, float q1, float q2,
    int r, const float* sM, const float* sB,
    float zeps, float sf,
    float& a0o, float& a1o, float& a2o) {
    const float* m = &sM[r * 9];
    // c = M[rel] @ child  (c_i = sum_j M[i][j] * child[j])
    float c0 = m[0] * q0 + m[1] * q1 + m[2] * q2;
    float c1 = m[3] * q0 + m[4] * q1 + m[5] * q2;
    float c2 = m[6] * q0 + m[7] * q1 + m[8] * q2;
    sparsemax3(c0, c1, c2, c0, c1, c2);
    sparsemax3(c0, c1, c2, c0, c1, c2);   // reference applies it twice
    sparsemax3(p0, p1, p2, p0, p1, p2);
    float b0 = sB[r * 3 + 0], b1 = sB[r * 3 + 1], b2 = sB[r * 3 + 2];
    float a0 = (1.0f - b0) * p0 + b0 * c0;
    float a1 = (1.0f - b1) * p1 + b1 * c1;
    float a2 = (1.0f - b2) * p2 + b2 * c2;
    // scale(): entropy of clamped, normalized mixture
    float z0 = fmaxf(p0 + c0, zeps);
    float z1 = fmaxf(p1 + c1, zeps);
    float z2 = fmaxf(p2 + c2, zeps);
    float zs = z0 + z1 + z2;
    z0 /= zs; z1 /= zs; z2 /= zs;
    float ent = -(z0 * logf(z0) + z1 * logf(z1) + z2 * logf(z2));
    // cosine similarity between p and (final) c
    float dot = p0 * c0 + p1 * c1 + p2 * c2;
    float np = sqrtf(p0 * p0 + p1 * p1 + p2 * p2);
    float nc = sqrtf(c0 * c0 + c1 * c1 + c2 * c2);
    float nrm = fmaxf(np * nc, 1e-10f);
    float cosv = 0.1f + dot / nrm;
    float scale = sf * cosv / ent;
    a0o = fmaxf(a0 * scale, 0.001f);
    a1o = fmaxf(a1 * scale, 0.001f);
    a2o = fmaxf(a2 * scale, 0.001f);
}

__global__ __launch_bounds__(BLOCK) void alpha_kernel(
    const float* __restrict__ prnt, const float* __restrict__ child,
    const float* __restrict__ Mg, const float* __restrict__ betag,
    const float* __restrict__ zeps_p, const float* __restrict__ sf_p,
    const int* __restrict__ rels, float* __restrict__ out, int n_edges) {
    __shared__ float sM[NRELS * 9];
    __shared__ float sB[NRELS * 3];
    for (int i = threadIdx.x; i < NRELS * 9; i += BLOCK) sM[i] = Mg[i];
    for (int i = threadIdx.x; i < NRELS * 3; i += BLOCK) sB[i] = betag[i];
    __syncthreads();

    const float zeps = zeps_p[0];
    const float sf   = sf_p[0];
    const int nt4 = n_edges >> 2;          // full groups of 4 edges
    int t = blockIdx.x * BLOCK + threadIdx.x;

    if (t < nt4) {
        // 16B/lane vectorized path: 4 edges per thread
        const float4* p4 = (const float4*)prnt;
        const float4* c4 = (const float4*)child;
        float4* o4 = (float4*)out;
        int4 r4 = ((const int4*)rels)[t];
        float4 pa = p4[3 * t + 0], pb = p4[3 * t + 1], pc = p4[3 * t + 2];
        float4 ca = c4[3 * t + 0], cb = c4[3 * t + 1], cc = c4[3 * t + 2];
        float P[12] = {pa.x, pa.y, pa.z, pa.w, pb.x, pb.y, pb.z, pb.w,
                       pc.x, pc.y, pc.z, pc.w};
        float C[12] = {ca.x, ca.y, ca.z, ca.w, cb.x, cb.y, cb.z, cb.w,
                       cc.x, cc.y, cc.z, cc.w};
        int R[4] = {r4.x, r4.y, r4.z, r4.w};
        float O[12];
        #pragma unroll
        for (int e = 0; e < 4; e++) {
            edge_compute(P[3 * e], P[3 * e + 1], P[3 * e + 2],
                         C[3 * e], C[3 * e + 1], C[3 * e + 2],
                         R[e], sM, sB, zeps, sf,
                         O[3 * e], O[3 * e + 1], O[3 * e + 2]);
        }
        float4 oa = {O[0], O[1], O[2],  O[3]};
        float4 ob = {O[4], O[5], O[6],  O[7]};
        float4 oc = {O[8], O[9], O[10], O[11]};
        o4[3 * t + 0] = oa;
        o4[3 * t + 1] = ob;
        o4[3 * t + 2] = oc;
    } else if (t == nt4) {
        // scalar tail for n_edges % 4 leftover edges (none for N=8M, defensive)
        for (int e = nt4 * 4; e < n_edges; e++) {
            float a0, a1, a2;
            edge_compute(prnt[3 * e], prnt[3 * e + 1], prnt[3 * e + 2],
                         child[3 * e], child[3 * e + 1], child[3 * e + 2],
                         rels[e], sM, sB, zeps, sf, a0, a1, a2);
            out[3 * e] = a0; out[3 * e + 1] = a1; out[3 * e + 2] = a2;
        }
    }
}

extern "C" void kernel_launch(void* const* d_in, const int* in_sizes, int n_in,
                              void* d_out, int out_size, void* d_ws, size_t ws_size,
                              hipStream_t stream) {
    const float* prnt  = (const float*)d_in[0];
    const float* child = (const float*)d_in[1];
    const float* Mg    = (const float*)d_in[2];
    const float* betag = (const float*)d_in[3];
    const float* zeps  = (const float*)d_in[4];
    const float* sf    = (const float*)d_in[5];
    const int*   rels  = (const int*)d_in[6];
    float* out = (float*)d_out;

    int n_edges = in_sizes[0] / 3;
    int nthreads = (n_edges >> 2) + 1;           // +1 thread for scalar tail
    int nblocks = (nthreads + BLOCK - 1) / BLOCK;
    alpha_kernel<<<nblocks, BLOCK, 0, stream>>>(
        prnt, child, Mg, betag, zeps, sf, rels, out, n_edges);
}

// Round 2
// 264.797 us; speedup vs baseline: 1.0052x; 1.0052x over previous
//
#include <hip/hip_runtime.h>

#define NRELS 64
#define BLOCK 256

// ln(x) via v_log_f32 (log2, ~1 ulp) * ln2. Inputs here are >= ~5e-3, well
// away from denormal trouble. Absolute output threshold is 0.675 on values
// up to ~454 -> ~1.5e-3 relative budget; these approximations are ~1e-7.
__device__ __forceinline__ float fast_ln(float x) {
    return 0.69314718056f * __builtin_amdgcn_logf(x);
}
__device__ __forceinline__ float fast_rcp(float x) {
    return __builtin_amdgcn_rcpf(x);
}
__device__ __forceinline__ float fast_rsq(float x) {
    return __builtin_amdgcn_rsqf(x);
}

// Faithful sparsemax for d=3 (Martins & Astudillo 2016), matching the
// reference: sort desc, cumsum, ksup = sum of support booleans,
// tau = (cs[ksup-1]-1)/ksup, out = max(z - tau, 0).
__device__ __forceinline__ void sparsemax3(float z0, float z1, float z2,
                                           float& o0, float& o1, float& o2) {
    float lo01 = fminf(z0, z1), hi01 = fmaxf(z0, z1);
    float s2 = fminf(lo01, z2);          // min of all
    float mx = fmaxf(lo01, z2);
    float s0 = fmaxf(hi01, mx);          // max of all
    float s1 = fminf(hi01, mx);          // middle
    float cs2 = s0 + s1;
    float cs3 = cs2 + s2;
    // k=1 support condition (1 + s0 > s0) is always true.
    bool k2 = (1.0f + 2.0f * s1 > cs2);
    bool k3 = (1.0f + 3.0f * s2 > cs3);
    int k = 1 + (int)k2 + (int)k3;
    float csk = (k == 1) ? s0 : ((k == 2) ? cs2 : cs3);
    float rk  = (k == 1) ? 1.0f : ((k == 2) ? 0.5f : 0.33333334f);
    float tau = (csk - 1.0f) * rk;
    o0 = fmaxf(z0 - tau, 0.0f);
    o1 = fmaxf(z1 - tau, 0.0f);
    o2 = fmaxf(z2 - tau, 0.0f);
}

__device__ __forceinline__ void edge_compute(
    float p0, float p1, float p2,
    float q0, float q1, float q2,
    int r, const float* sM, const float* sB,
    float zeps, float sf,
    float& a0o, float& a1o, float& a2o) {
    // M row-major 3x3 padded to 12 floats/rel: 2x ds_read_b128 + 1x b32.
    const float4 ma = *(const float4*)&sM[r * 12];       // m00 m01 m02 m10
    const float4 mb = *(const float4*)&sM[r * 12 + 4];   // m11 m12 m20 m21
    const float  m22 = sM[r * 12 + 8];
    float c0 = ma.x * q0 + ma.y * q1 + ma.z * q2;
    float c1 = ma.w * q0 + mb.x * q1 + mb.y * q2;
    float c2 = mb.z * q0 + mb.w * q1 + m22 * q2;
    sparsemax3(c0, c1, c2, c0, c1, c2);
    sparsemax3(c0, c1, c2, c0, c1, c2);   // reference applies it twice
    sparsemax3(p0, p1, p2, p0, p1, p2);
    const float4 bv = *(const float4*)&sB[r * 4];        // b0 b1 b2 pad
    float a0 = (1.0f - bv.x) * p0 + bv.x * c0;
    float a1 = (1.0f - bv.y) * p1 + bv.y * c1;
    float a2 = (1.0f - bv.z) * p2 + bv.z * c2;
    // scale(): entropy of clamped, normalized mixture
    float z0 = fmaxf(p0 + c0, zeps);
    float z1 = fmaxf(p1 + c1, zeps);
    float z2 = fmaxf(p2 + c2, zeps);
    float rs = fast_rcp(z0 + z1 + z2);
    z0 *= rs; z1 *= rs; z2 *= rs;
    float ent = -(z0 * fast_ln(z0) + z1 * fast_ln(z1) + z2 * fast_ln(z2));
    // cosine similarity between p and (final) c.
    // p and c each sum to 1 (sparsemax outputs) -> |p|^2,|c|^2 >= 1/3, so the
    // 1e-10 guard in the reference never binds; guard the squared product.
    float dot = p0 * c0 + p1 * c1 + p2 * c2;
    float pp = p0 * p0 + p1 * p1 + p2 * p2;
    float cc = c0 * c0 + c1 * c1 + c2 * c2;
    float cosv = 0.1f + dot * fast_rsq(fmaxf(pp * cc, 1e-20f));
    float scale = sf * cosv * fast_rcp(ent);
    a0o = fmaxf(a0 * scale, 0.001f);
    a1o = fmaxf(a1 * scale, 0.001f);
    a2o = fmaxf(a2 * scale, 0.001f);
}

__global__ __launch_bounds__(BLOCK) void alpha_kernel(
    const float* __restrict__ prnt, const float* __restrict__ child,
    const float* __restrict__ Mg, const float* __restrict__ betag,
    const float* __restrict__ zeps_p, const float* __restrict__ sf_p,
    const int* __restrict__ rels, float* __restrict__ out, int n_edges) {
    // stride 12 floats (48 B) for M: b128 start bank cycles through 8 distinct
    // positions -> spreads the random-gather conflicts; stride 4 for beta.
    __shared__ __align__(16) float sM[NRELS * 12];
    __shared__ __align__(16) float sB[NRELS * 4];
    for (int i = threadIdx.x; i < NRELS * 9; i += BLOCK) {
        int r = i / 9, rem = i - r * 9;
        sM[r * 12 + rem] = Mg[i];
    }
    for (int i = threadIdx.x; i < NRELS * 3; i += BLOCK) {
        int r = i / 3, rem = i - r * 3;
        sB[r * 4 + rem] = betag[i];
    }
    __syncthreads();

    const float zeps = zeps_p[0];
    const float sf   = sf_p[0];
    const int nt4 = n_edges >> 2;          // full groups of 4 edges
    int t = blockIdx.x * BLOCK + threadIdx.x;

    if (t < nt4) {
        // 16B/lane vectorized path: 4 edges per thread
        const float4* p4 = (const float4*)prnt;
        const float4* c4 = (const float4*)child;
        float4* o4 = (float4*)out;
        int4 r4 = ((const int4*)rels)[t];
        float4 pa = p4[3 * t + 0], pb = p4[3 * t + 1], pc = p4[3 * t + 2];
        float4 ca = c4[3 * t + 0], cb = c4[3 * t + 1], cc = c4[3 * t + 2];
        float P[12] = {pa.x, pa.y, pa.z, pa.w, pb.x, pb.y, pb.z, pb.w,
                       pc.x, pc.y, pc.z, pc.w};
        float C[12] = {ca.x, ca.y, ca.z, ca.w, cb.x, cb.y, cb.z, cb.w,
                       cc.x, cc.y, cc.z, cc.w};
        int R[4] = {r4.x, r4.y, r4.z, r4.w};
        float O[12];
        #pragma unroll
        for (int e = 0; e < 4; e++) {
            edge_compute(P[3 * e], P[3 * e + 1], P[3 * e + 2],
                         C[3 * e], C[3 * e + 1], C[3 * e + 2],
                         R[e], sM, sB, zeps, sf,
                         O[3 * e], O[3 * e + 1], O[3 * e + 2]);
        }
        float4 oa = {O[0], O[1], O[2],  O[3]};
        float4 ob = {O[4], O[5], O[6],  O[7]};
        float4 oc = {O[8], O[9], O[10], O[11]};
        o4[3 * t + 0] = oa;
        o4[3 * t + 1] = ob;
        o4[3 * t + 2] = oc;
    } else if (t == nt4) {
        // scalar tail for n_edges % 4 leftover edges (none for N=8M, defensive)
        for (int e = nt4 * 4; e < n_edges; e++) {
            float a0, a1, a2;
            edge_compute(prnt[3 * e], prnt[3 * e + 1], prnt[3 * e + 2],
                         child[3 * e], child[3 * e + 1], child[3 * e + 2],
                         rels[e], sM, sB, zeps, sf, a0, a1, a2);
            out[3 * e] = a0; out[3 * e + 1] = a1; out[3 * e + 2] = a2;
        }
    }
}

extern "C" void kernel_launch(void* const* d_in, const int* in_sizes, int n_in,
                              void* d_out, int out_size, void* d_ws, size_t ws_size,
                              hipStream_t stream) {
    const float* prnt  = (const float*)d_in[0];
    const float* child = (const float*)d_in[1];
    const float* Mg    = (const float*)d_in[2];
    const float* betag = (const float*)d_in[3];
    const float* zeps  = (const float*)d_in[4];
    const float* sf    = (const float*)d_in[5];
    const int*   rels  = (const int*)d_in[6];
    float* out = (float*)d_out;

    int n_edges = in_sizes[0] / 3;
    int nthreads = (n_edges >> 2) + 1;           // +1 thread for scalar tail
    int nblocks = (nthreads + BLOCK - 1) / BLOCK;
    alpha_kernel<<<nblocks, BLOCK, 0, stream>>>(
        prnt, child, Mg, betag, zeps, sf, rels, out, n_edges);
}